// Round 5
// baseline (233.656 us; speedup 1.0000x reference)
//
#include <hip/hip_runtime.h>

#define NG 76
#define NPOS (NG * NG)              // 5776
#define NC 85                       // 5 + 80
#define NA 3
#define PPB 256                     // positions per block, 1 per thread
#define TPP ((NPOS + PPB - 1) / PPB)  // 23 position-blocks per plane
#define STRIDE_F 8.0f               // 608 / 76

typedef float f4 __attribute__((ext_vector_type(4)));

// exp(w) * scaled_anchor * stride == exp(w) * ANCHOR  (scaled = ANCHOR/stride)
__constant__ float c_aw[NA] = {10.0f, 16.0f, 33.0f};
__constant__ float c_ah[NA] = {13.0f, 30.0f, 23.0f};

__device__ __forceinline__ float sigm(float x) {
    return __builtin_amdgcn_rcpf(1.0f + __expf(-x));
}

// 16B store at 4B alignment: out offset p*85+c has (p%4) misalignment.
// memcpy lets clang emit global_store_dwordx4 align-4 (legal on gfx950)
// or split legally — correct either way.
__device__ __forceinline__ void store_f4(float* p, f4 v) {
    __builtin_memcpy(p, &v, 16);
}

// One thread = one grid position. No LDS, no barriers, no phases.
// Reads:  for fixed channel c, lanes hold consecutive p -> 256 B coalesced
//         per instruction; 85 independent loads/thread -> deep MLP.
// Writes: thread's 85 outputs are contiguous (340 B); the wave covers a
//         contiguous 21.7 KB span -> L2 write-merges full lines.
__global__ __launch_bounds__(PPB) void det_kernel(const float* __restrict__ in,
                                                  float* __restrict__ out) {
    const int plane = blockIdx.y;                 // b*NA + a
    const int a     = plane - (plane / NA) * NA;
    const int p     = blockIdx.x * PPB + threadIdx.x;
    if (p >= NPOS) return;                        // tail block: 144 active

    const float aw = c_aw[a];
    const float ah = c_ah[a];

    const float* ip = in  + (size_t)plane * (NC * NPOS) + p;   // ch stride NPOS
    float*       op = out + ((size_t)plane * NPOS + p) * NC;

    const int gy = (int)((unsigned)p / (unsigned)NG);          // once per thread
    const int gx = p - gy * NG;

    // ---- head group: box x, y, w, h (compile-time channels 0..3) ----
    const float bx = ip[0 * NPOS];
    const float by = ip[1 * NPOS];
    const float bw = ip[2 * NPOS];
    const float bh = ip[3 * NPOS];
    f4 o0;
    o0.x = (sigm(bx) + (float)gx) * STRIDE_F;
    o0.y = (sigm(by) + (float)gy) * STRIDE_F;
    o0.z = __expf(bw) * aw;
    o0.w = __expf(bh) * ah;
    store_f4(op, o0);

    // ---- 20 pure-sigmoid groups: channels 4..83 ----
    #pragma unroll
    for (int g = 0; g < 20; ++g) {
        const int c = 4 + g * 4;
        f4 v;
        v.x = ip[(c + 0) * NPOS];
        v.y = ip[(c + 1) * NPOS];
        v.z = ip[(c + 2) * NPOS];
        v.w = ip[(c + 3) * NPOS];
        f4 r;
        r.x = sigm(v.x);
        r.y = sigm(v.y);
        r.z = sigm(v.z);
        r.w = sigm(v.w);
        store_f4(op + c, r);
    }

    // ---- tail: channel 84 ----
    op[84] = sigm(ip[84 * NPOS]);
}

extern "C" void kernel_launch(void* const* d_in, const int* in_sizes, int n_in,
                              void* d_out, int out_size, void* d_ws, size_t ws_size,
                              hipStream_t stream) {
    const float* x = (const float*)d_in[0];
    float* out     = (float*)d_out;
    const int nB   = in_sizes[0] / (NA * NC * NPOS);   // 16
    dim3 grid(TPP, nB * NA);                           // 23 x 48
    det_kernel<<<grid, PPB, 0, stream>>>(x, out);
}

// Round 6
// 166.624 us; speedup vs baseline: 1.4023x; 1.4023x over previous
//
#include <hip/hip_runtime.h>

#define NG 76
#define NPOS (NG * NG)            // 5776
#define NC 85                     // 5 + 80
#define NA 3
#define SPOS 16                   // positions per wave-strip
#define SPP (NPOS / SPOS)         // 361 strips per plane (exact)
#define WPB 4                     // waves per block (256 threads)
#define STRIDE_F 8.0f             // 608 / 76

typedef float f4 __attribute__((ext_vector_type(4)));

// exp(w) * scaled_anchor * stride == exp(w) * ANCHOR  (scaled = ANCHOR/stride)
__constant__ float c_aw[NA] = {10.0f, 16.0f, 33.0f};
__constant__ float c_ah[NA] = {13.0f, 30.0f, 23.0f};

__device__ __forceinline__ float rcpf(float x) { return __builtin_amdgcn_rcpf(x); }

// One WAVE = one 16-position strip. LDS region is wave-private, so there is
// no __syncthreads anywhere: waves on a SIMD interleave their load / LDS /
// compute / store phases freely instead of convoying at block barriers.
__global__ __launch_bounds__(256) void det_kernel(const float* __restrict__ in,
                                                  float* __restrict__ out) {
    __shared__ __align__(16) float lds[WPB][SPOS * NC];   // 4 x 5440 B

    const int t   = threadIdx.x;
    const int w   = t >> 6;                               // wave in block
    const int l   = t & 63;                               // lane
    const int sid = blockIdx.x * WPB + w;                 // global strip id
    const int plane = (int)((unsigned)sid / (unsigned)SPP);  // b*NA + a
    const int strip = sid - plane * SPP;
    const int a     = plane - (plane / NA) * NA;
    const int pos0  = strip * SPOS;
    const float aw = c_aw[a];
    const float ah = c_ah[a];

    const float* ip = in  + (size_t)plane * (NC * NPOS) + pos0;
    float*       op = out + (size_t)plane * (NPOS * NC) + (size_t)pos0 * NC;
    float* L = lds[w];

    constexpr int NV = NC * 4;                            // 340 f4 per strip

    // ---- coalesced load + scatter-transpose into wave-private LDS ----
    #pragma unroll
    for (int i = 0; i < 6; ++i) {
        int v = l + i * 64;
        v = v < NV ? v : NV - 1;                          // clamp: dups benign
        const int c  = v >> 2;
        const int pq = v & 3;
        const f4 f = *reinterpret_cast<const f4*>(ip + c * NPOS + pq * 4);
        const int pb = pq * 4;
        L[(pb + 0) * NC + c] = f.x;   // <=3-way bank alias: free (m136)
        L[(pb + 1) * NC + c] = f.y;
        L[(pb + 2) * NC + c] = f.z;
        L[(pb + 3) * NC + c] = f.w;
    }
    // Wave-synchronous LDS handoff: DS pipe is in-order per wave; the
    // explicit waitcnt + memory clobber pins compile-time ordering (the
    // cross-lane dependence is invisible to per-thread alias analysis).
    asm volatile("s_waitcnt lgkmcnt(0)" ::: "memory");

    // ---- ds_read_b128 + single-exp transform + coalesced store ----
    #pragma unroll
    for (int i = 0; i < 6; ++i) {
        int v = l + i * 64;
        v = v < NV ? v : NV - 1;                          // dup store: benign
        const int e0 = v * 4;
        const f4 f = *reinterpret_cast<const f4*>(&L[e0]);
        const int p0 = (int)((unsigned)e0 / (unsigned)NC);   // magic mul
        const int c0 = e0 - p0 * NC;
        const int posA = pos0 + p0;
        const int gyA  = (int)((unsigned)posA / (unsigned)NG);
        const int gxA  = posA - gyA * NG;
        const bool wrapRow = (gxA == NG - 1);
        const float gxAf = (float)gxA, gyAf = (float)gyA;
        const float gxBf = wrapRow ? 0.0f : gxAf + 1.0f;
        const float gyBf = wrapRow ? gyAf + 1.0f : gyAf;

        const float xin[4] = {f.x, f.y, f.z, f.w};
        float res[4];
        int p = p0, c = c0;
        #pragma unroll
        for (int k = 0; k < 4; ++k) {
            const float x    = xin[k];
            const bool iswh  = (c == 2) || (c == 3);
            const bool isxy  = (c < 2);
            const float e    = __expf(iswh ? x : -x);     // ONE transcendental
            const float sg   = rcpf(1.0f + e);
            const float gx   = (p != p0) ? gxBf : gxAf;
            const float gy   = (p != p0) ? gyBf : gyAf;
            const float g    = (c == 0) ? gx : gy;
            const float mul  = isxy ? STRIDE_F : (iswh ? ((c == 2) ? aw : ah) : 1.0f);
            const float add  = isxy ? g * STRIDE_F : 0.0f;
            res[k] = fmaf(iswh ? e : sg, mul, add);
            if (++c == NC) { c = 0; ++p; }
        }
        f4 o = {res[0], res[1], res[2], res[3]};
        *reinterpret_cast<f4*>(op + e0) = o;
    }
}

extern "C" void kernel_launch(void* const* d_in, const int* in_sizes, int n_in,
                              void* d_out, int out_size, void* d_ws, size_t ws_size,
                              hipStream_t stream) {
    const float* x = (const float*)d_in[0];
    float* out     = (float*)d_out;
    const int nB     = in_sizes[0] / (NA * NC * NPOS);    // 16
    const int blocks = nB * NA * SPP / WPB;               // 17328/4 = 4332
    det_kernel<<<blocks, 256, 0, stream>>>(x, out);
}

// Round 7
// 165.878 us; speedup vs baseline: 1.4086x; 1.0045x over previous
//
#include <hip/hip_runtime.h>

#define NG 76
#define NPOS (NG * NG)            // 5776
#define NC 85                     // 5 + 80
#define NA 3
#define SPOS 16                   // positions per wave-strip
#define SPP (NPOS / SPOS)         // 361 strips per plane (exact)
#define WPB 4                     // waves per block (256 threads)
#define STRIDE_F 8.0f             // 608 / 76

typedef float f4 __attribute__((ext_vector_type(4)));

// exp(w) * scaled_anchor * stride == exp(w) * ANCHOR  (scaled = ANCHOR/stride)
__constant__ float c_aw[NA] = {10.0f, 16.0f, 33.0f};
__constant__ float c_ah[NA] = {13.0f, 30.0f, 23.0f};

__device__ __forceinline__ float sigm(float x) {
    return __builtin_amdgcn_rcpf(1.0f + __expf(-x));
}

// R6 structure (wave-private LDS strip, no barriers) with ONE change:
// the transform moves to the LOAD phase, where each f4 holds 4 consecutive
// positions of ONE channel -> channel class is uniform per vector, and
// iterations 1..5 are provably pure-sigmoid (c = (l+64i)>>2 >= 16).
// The store phase becomes a pure LDS->global copy (no VALU).
__global__ __launch_bounds__(256) void det_kernel(const float* __restrict__ in,
                                                  float* __restrict__ out) {
    __shared__ __align__(16) float lds[WPB][SPOS * NC];   // 4 x 5440 B

    const int t   = threadIdx.x;
    const int w   = t >> 6;                               // wave in block
    const int l   = t & 63;                               // lane
    const int sid = blockIdx.x * WPB + w;                 // global strip id
    const int plane = (int)((unsigned)sid / (unsigned)SPP);  // b*NA + a
    const int strip = sid - plane * SPP;
    const int a     = plane - (plane / NA) * NA;
    const int pos0  = strip * SPOS;
    const float aw = c_aw[a];
    const float ah = c_ah[a];

    const float* ip = in  + (size_t)plane * (NC * NPOS) + pos0;
    float*       op = out + (size_t)plane * (NPOS * NC) + (size_t)pos0 * NC;
    float* L = lds[w];

    constexpr int NV = NC * 4;                            // 340 f4 per strip

    // ---- iter 0: channels 0..15 (mixed classes, only divergent iter) ----
    {
        const int c  = l >> 2;                            // 0..15
        const int pq = l & 3;
        const f4 f = *reinterpret_cast<const f4*>(ip + c * NPOS + pq * 4);
        f4 r;
        if (c >= 4) {                                     // conf/classes
            r.x = sigm(f.x); r.y = sigm(f.y); r.z = sigm(f.z); r.w = sigm(f.w);
        } else if (c == 2) {                              // box w
            r.x = __expf(f.x) * aw; r.y = __expf(f.y) * aw;
            r.z = __expf(f.z) * aw; r.w = __expf(f.w) * aw;
        } else if (c == 3) {                              // box h
            r.x = __expf(f.x) * ah; r.y = __expf(f.y) * ah;
            r.z = __expf(f.z) * ah; r.w = __expf(f.w) * ah;
        } else {
            // c==0/1: 4 consecutive positions, 4-aligned group (76%4==0)
            // -> never crosses a grid row: gy uniform, gx = gx0+k.
            const int pbase = pos0 + pq * 4;
            const int gy  = (int)((unsigned)pbase / (unsigned)NG);
            const int gx0 = pbase - gy * NG;
            if (c == 0) {
                const float g0 = (float)gx0;
                r.x = (sigm(f.x) + g0)        * STRIDE_F;
                r.y = (sigm(f.y) + g0 + 1.0f) * STRIDE_F;
                r.z = (sigm(f.z) + g0 + 2.0f) * STRIDE_F;
                r.w = (sigm(f.w) + g0 + 3.0f) * STRIDE_F;
            } else {
                const float gyf = (float)gy;
                r.x = (sigm(f.x) + gyf) * STRIDE_F;
                r.y = (sigm(f.y) + gyf) * STRIDE_F;
                r.z = (sigm(f.z) + gyf) * STRIDE_F;
                r.w = (sigm(f.w) + gyf) * STRIDE_F;
            }
        }
        const int pb = pq * 4;
        L[(pb + 0) * NC + c] = r.x;                       // <=3-way alias: free
        L[(pb + 1) * NC + c] = r.y;
        L[(pb + 2) * NC + c] = r.z;
        L[(pb + 3) * NC + c] = r.w;
    }

    // ---- iters 1..5: c = (l+64i)>>2 >= 16 -> pure sigmoid, no decode ----
    #pragma unroll
    for (int i = 1; i < 6; ++i) {
        int v = l + i * 64;
        v = v < NV ? v : NV - 1;                          // clamp: dups benign
        const int c  = v >> 2;
        const int pq = v & 3;
        const f4 f = *reinterpret_cast<const f4*>(ip + c * NPOS + pq * 4);
        f4 r;
        r.x = sigm(f.x); r.y = sigm(f.y); r.z = sigm(f.z); r.w = sigm(f.w);
        const int pb = pq * 4;
        L[(pb + 0) * NC + c] = r.x;
        L[(pb + 1) * NC + c] = r.y;
        L[(pb + 2) * NC + c] = r.z;
        L[(pb + 3) * NC + c] = r.w;
    }

    // Wave-synchronous LDS handoff (DS pipe in-order per wave); clobber pins
    // compile-time ordering of the cross-lane dependence. Proven in R6.
    asm volatile("s_waitcnt lgkmcnt(0)" ::: "memory");

    // ---- store phase: pure LDS->global copy, zero VALU ----
    #pragma unroll
    for (int i = 0; i < 6; ++i) {
        int v = l + i * 64;
        v = v < NV ? v : NV - 1;                          // dup store benign
        const f4 o = *reinterpret_cast<const f4*>(&L[v * 4]);
        *reinterpret_cast<f4*>(op + v * 4) = o;
    }
}

extern "C" void kernel_launch(void* const* d_in, const int* in_sizes, int n_in,
                              void* d_out, int out_size, void* d_ws, size_t ws_size,
                              hipStream_t stream) {
    const float* x = (const float*)d_in[0];
    float* out     = (float*)d_out;
    const int nB     = in_sizes[0] / (NA * NC * NPOS);    // 16
    const int blocks = nB * NA * SPP / WPB;               // 17328/4 = 4332
    det_kernel<<<blocks, 256, 0, stream>>>(x, out);
}